// Round 5
// baseline (273.871 us; speedup 1.0000x reference)
//
#include <hip/hip_runtime.h>
#include <hip/hip_fp16.h>
#include <math.h>

#define N_NODES 100000
#define N_EDGES 1600000
#define F_IN 8
#define HID 32
#define HEADS 4
#define F1 128    // HEADS*HID
#define F2 16     // OUT
#define NB 391          // buckets of 256 nodes
#define NBLK_BIN 391    // edge-binning blocks of 4096 edges
#define NBLK_A 391      // a_s1/a_d1 blocks of 256 nodes
#define BCAP 4864       // per-bucket capacity (mean 4092, sd ~64 -> 12 sigma)

__device__ __forceinline__ float leaky(float x){ return x > 0.f ? x : 0.2f * x; }
__device__ __forceinline__ float elu1(float x){ return x > 0.f ? x : __expf(x) - 1.f; }

// XOR swizzle for W2s (dword addr): bank of a is independent of l-stride 128
// (128 % 32 == 0) -> XOR bits[9:7] into bits[4:2]. Involution. (round-3 proven)
__device__ __forceinline__ int swz(int a){ return a ^ (((a >> 7) & 7) << 2); }
// XOR swizzle for W1s (dword addr): element a stored at a ^ (bit5(a)<<2).
// Epilogue reads a = m*128 + 8l (+4); lanes l and l+4 share a bank otherwise.
// NOTE (round-4 bug): the swizzle is an involution on each 4-dword span, NOT
// an offset -- the second half of the 8-dword fragment is at (dsw ^ 4), not
// (dsw + 4). dsw+4 walked past W1s[1024] for d0=120,m=7 -> NaN from garbage LDS.
__device__ __forceinline__ int swz1(int a){ return a ^ (((a >> 5) & 1) << 2); }

// ---------------- Fused: edge binning (blocks 0..390) + attention dots (rest) ----------------
// a_s1[n,h] = h1[n,h,:]·att_s[h,:] = x[n,:]·c_s[h,:] with c_s[h] = W1_h @ att_s[h]
// (8 floats per head) -- no need to materialize h1 at all.
__global__ __launch_bounds__(256) void k_bin_attn(
    const int* __restrict__ src, const int* __restrict__ dst,
    int* __restrict__ bucketCnt, unsigned int* __restrict__ ebuf,
    const float* __restrict__ x, const float* __restrict__ W1,
    const float* __restrict__ as1w, const float* __restrict__ ad1w,
    float* __restrict__ a_s1, float* __restrict__ a_d1){
    __shared__ float smem[1344];
    int t = threadIdx.x;
    if (blockIdx.x < NBLK_BIN){
        // ---- edge binning: 4096 edges -> 391 coarse buckets, line-local writes ----
        int* hist    = (int*)smem;
        int* basePos = hist + NB;
        int* cur     = basePos + NB;
        for (int j = t; j < NB; j += 256) hist[j] = 0;
        __syncthreads();
        int base = blockIdx.x * 4096;
        int dv[16];                        // register-cache dst (skip re-read in scatter pass)
        #pragma unroll
        for (int j = 0; j < 16; j++){
            int e = base + j * 256 + t;
            dv[j] = (e < N_EDGES) ? dst[e] : -1;
            if (dv[j] >= 0) atomicAdd(&hist[dv[j] >> 8], 1);
        }
        __syncthreads();
        for (int j = t; j < NB; j += 256){
            int h = hist[j];
            if (h) basePos[j] = atomicAdd(&bucketCnt[j], h);
            cur[j] = 0;
        }
        __syncthreads();
        #pragma unroll
        for (int j = 0; j < 16; j++){
            if (dv[j] >= 0){
                int e = base + j * 256 + t;
                int d = dv[j];
                int b = d >> 8;
                int off = atomicAdd(&cur[b], 1);
                ebuf[b * BCAP + basePos[b] + off] = ((unsigned)(d & 255) << 17) | (unsigned)src[e];
            }
        }
    } else {
        // ---- attention dots: c = W1·att (per block, tiny), then a_s1/a_d1 per node ----
        float* W1s  = smem;          // 1024
        float* atts = smem + 1024;   // 128
        float* attd = smem + 1152;   // 128
        float* cs   = smem + 1280;   // 32  (cs[h*8+m])
        float* cd   = smem + 1312;   // 32
        ((float4*)W1s)[t] = ((const float4*)W1)[t];
        if (t < 128){ atts[t] = as1w[t]; attd[t] = ad1w[t]; }
        __syncthreads();
        if (t < 64){
            int m = t & 7, h = (t >> 3) & 3;
            bool sel = t >= 32;
            const float* wrow = W1s + m * F1 + h * 32;
            const float* av   = (sel ? attd : atts) + h * 32;
            float s = 0.f;
            #pragma unroll
            for (int d = 0; d < 32; d++) s += wrow[d] * av[d];
            (sel ? cd : cs)[h * 8 + m] = s;
        }
        __syncthreads();
        int n = (blockIdx.x - NBLK_BIN) * 256 + t;
        if (n < N_NODES){
            float4 x0 = ((const float4*)x)[n * 2];
            float4 x1 = ((const float4*)x)[n * 2 + 1];
            float4 osv, odv;
            float* po = (float*)&osv;
            float* pd = (float*)&odv;
            #pragma unroll
            for (int h = 0; h < 4; h++){
                const float* c0 = cs + h * 8;
                const float* c1 = cd + h * 8;
                po[h] = x0.x*c0[0] + x0.y*c0[1] + x0.z*c0[2] + x0.w*c0[3]
                      + x1.x*c0[4] + x1.y*c0[5] + x1.z*c0[6] + x1.w*c0[7];
                pd[h] = x0.x*c1[0] + x0.y*c1[1] + x0.z*c1[2] + x0.w*c1[3]
                      + x1.x*c1[4] + x1.y*c1[5] + x1.z*c1[6] + x1.w*c1[7];
            }
            *(float4*)(a_s1 + (size_t)n * 4) = osv;
            *(float4*)(a_d1 + (size_t)n * 4) = odv;
        }
    }
}

// ---------------- CSR pass 2: one 256-thread block per bucket ----------------
__global__ __launch_bounds__(256) void k_local_csr(
    const int* __restrict__ bucketCnt, const unsigned int* __restrict__ ebuf,
    int* __restrict__ row_ptr, int* __restrict__ esrc){
    __shared__ int deg[256];
    __shared__ int scn[256];
    __shared__ int cntAll[NB];
    __shared__ unsigned int segs[BCAP];   // LDS cache of this bucket's edges (19.5 KB)
    int b = blockIdx.x, t = threadIdx.x;
    deg[t] = 0;
    for (int j = t; j < NB; j += 256) cntAll[j] = bucketCnt[j];
    __syncthreads();
    // parallel bucket-prefix: sum cntAll[0..b) across all 256 threads
    int partial = 0;
    for (int j = t; j < b; j += 256) partial += cntAll[j];
    scn[t] = partial;
    __syncthreads();
    for (int off = 128; off > 0; off >>= 1){
        if (t < off) scn[t] += scn[t + off];
        __syncthreads();
    }
    int sbase = scn[0];
    int cnt = cntAll[b];
    __syncthreads();
    const unsigned int* seg = ebuf + b * BCAP;
    for (int i = t; i < cnt; i += 256){
        unsigned int e = seg[i];
        segs[i] = e;                      // cache for scatter pass (kills 2nd global read)
        atomicAdd(&deg[e >> 17], 1);
    }
    __syncthreads();
    int v = deg[t];
    scn[t] = v;
    __syncthreads();
    for (int off = 1; off < 256; off <<= 1){
        int xx = (t >= off) ? scn[t - off] : 0;
        __syncthreads();
        scn[t] += xx;
        __syncthreads();
    }
    int excl = scn[t] - v;
    int start = sbase + excl;
    int n = b * 256 + t;
    if (n < N_NODES) row_ptr[n] = start;
    if (b == NB - 1 && t == 0) row_ptr[N_NODES] = sbase + cnt;
    deg[t] = start;            // reuse as global cursor
    __syncthreads();
    for (int i = t; i < cnt; i += 256){
        unsigned int e = segs[i];
        int pos = atomicAdd(&deg[e >> 17], 1);
        esrc[pos] = (int)(e & 0x1FFFFu);
    }
}

// ---------------- Layer 1 aggregate (x-space) + FUSED layer-2 dense ----------------
// GAT layer 1 is linear in h: out[n,h,:] = (sum_e alpha_e x[src_e,:]) @ W1_h.
// So aggregate 8-dim x rows (32 B gathers, L2-resident) instead of 128-dim h1
// rows (256 B HBM gathers) -- 16x less gather payload, fp32 end-to-end.
// Layout: 4 edge-groups (g) x 16 lanes (l); lane owns head hd=l>>2, x-dims
// 2(l&3)..+1, fp32 acc. After xor16/32 + in-nibble shfl broadcast every lane
// holds xagg[hd][0..8]; it recomputes hL1 dims 8l..8l+7 via W1 (swizzled LDS)
// and runs the round-3-proven dense-2 epilogue (swizzled W2s) unchanged.
__global__ __launch_bounds__(256) void k_agg1(
    const float* __restrict__ x, const float* __restrict__ a_s1, const float* __restrict__ a_d1,
    const int* __restrict__ row_ptr, const int* __restrict__ esrc,
    const float* __restrict__ b1, const float* __restrict__ W1, const float* __restrict__ W2,
    const float* __restrict__ as2w, const float* __restrict__ ad2w,
    __half* __restrict__ h2h, float* __restrict__ a_s2, float* __restrict__ a_d2){
    __shared__ float W2s[F1 * F2];   // 8 KB, swz-swizzled
    __shared__ float W1s[F_IN * F1]; // 4 KB, swz1-swizzled
    int t = threadIdx.x;
    {
        float4 v0 = ((const float4*)W2)[t];
        float4 v1 = ((const float4*)W2)[t + 256];
        *(float4*)(W2s + swz(4 * t))         = v0;
        *(float4*)(W2s + swz(4 * (t + 256))) = v1;
        float4 w1v = ((const float4*)W1)[t];
        *(float4*)(W1s + swz1(4 * t)) = w1v;
    }
    __syncthreads();

    int wv = t >> 6, lane = t & 63;
    int n = blockIdx.x * 4 + wv;               // N divisible by 4
    int g = lane >> 4;                          // edge subgroup (0..3)
    int l = lane & 15;
    int hd = l >> 2;                            // head
    int c  = l & 3;                             // x-dim pair: 2c, 2c+1

    float adh = a_d1[(unsigned)(n * 4 + hd)];
    float den = 0.f, ac0 = 0.f, ac1 = 0.f;
    const float* xb = x + 2 * c;               // lane's 2-dim slice base

    if (g == 0){
        // self-loop (softmax shift m=0; logits O(1), fp32 acc -> no range hack)
        float w = __expf(leaky(a_s1[(unsigned)(n * 4 + hd)] + adh));
        den = w;
        float2 xv = *(const float2*)(xb + (size_t)n * 8);
        ac0 = w * xv.x; ac1 = w * xv.y;
    }
    int start = row_ptr[n], end = row_ptr[n + 1];
    int len = end - start;
    int chunk = (len + 3) >> 2;
    int i = start + g * chunk;
    int e = i + chunk; if (e > end) e = end;
    for (; i + 3 < e; i += 4){
        int s0 = esrc[i], s1 = esrc[i + 1], s2 = esrc[i + 2], s3 = esrc[i + 3];
        float a0 = a_s1[(unsigned)(s0 * 4 + hd)];
        float a1 = a_s1[(unsigned)(s1 * 4 + hd)];
        float a2 = a_s1[(unsigned)(s2 * 4 + hd)];
        float a3 = a_s1[(unsigned)(s3 * 4 + hd)];
        float2 x0 = *(const float2*)(xb + (size_t)s0 * 8);
        float2 x1 = *(const float2*)(xb + (size_t)s1 * 8);
        float2 x2 = *(const float2*)(xb + (size_t)s2 * 8);
        float2 x3 = *(const float2*)(xb + (size_t)s3 * 8);
        float w0 = __expf(leaky(a0 + adh));
        float w1 = __expf(leaky(a1 + adh));
        float w2 = __expf(leaky(a2 + adh));
        float w3 = __expf(leaky(a3 + adh));
        den += (w0 + w1) + (w2 + w3);
        ac0 = fmaf(w0, x0.x, ac0); ac1 = fmaf(w0, x0.y, ac1);
        ac0 = fmaf(w1, x1.x, ac0); ac1 = fmaf(w1, x1.y, ac1);
        ac0 = fmaf(w2, x2.x, ac0); ac1 = fmaf(w2, x2.y, ac1);
        ac0 = fmaf(w3, x3.x, ac0); ac1 = fmaf(w3, x3.y, ac1);
    }
    for (; i < e; i++){
        int s0 = esrc[i];
        float w0 = __expf(leaky(a_s1[(unsigned)(s0 * 4 + hd)] + adh));
        float2 x0 = *(const float2*)(xb + (size_t)s0 * 8);
        den += w0;
        ac0 = fmaf(w0, x0.x, ac0); ac1 = fmaf(w0, x0.y, ac1);
    }
    // combine the four edge-groups (lanes xor16/xor32 share l, hd)
    den += __shfl_xor(den, 16); den += __shfl_xor(den, 32);
    ac0 += __shfl_xor(ac0, 16); ac0 += __shfl_xor(ac0, 32);
    ac1 += __shfl_xor(ac1, 16); ac1 += __shfl_xor(ac1, 32);

    // broadcast xagg[hd][0..8] from the 4 lanes of this head (any g; use g=0's)
    int lb = l & 12;                           // = hd*4
    float xa[8];
    #pragma unroll
    for (int j = 0; j < 4; j++){
        xa[2 * j]     = __shfl(ac0, lb + j);
        xa[2 * j + 1] = __shfl(ac1, lb + j);
    }

    // ---- hL1 dims 8l..8l+7: (xagg @ W1_h)/den + b1, elu (all lanes) ----
    float inv = 1.f / den;                     // den >= self-loop w > 0
    int d0 = l * 8;
    int j0 = g << 2;
    int dsw = d0 ^ (((d0 >> 5) & 1) << 2);     // swizzled addr of elems d0..d0+3
    // elems d0+4..d0+7 live at dsw^4 (involution!), NOT dsw+4 (round-4 bug: OOB)
    float pre[8] = {0,0,0,0,0,0,0,0};
    #pragma unroll
    for (int m = 0; m < 8; m++){
        float4 wa = *(const float4*)(W1s + m * F1 + dsw);
        float4 wb = *(const float4*)(W1s + m * F1 + (dsw ^ 4));
        float xm = xa[m];
        pre[0] = fmaf(xm, wa.x, pre[0]); pre[1] = fmaf(xm, wa.y, pre[1]);
        pre[2] = fmaf(xm, wa.z, pre[2]); pre[3] = fmaf(xm, wa.w, pre[3]);
        pre[4] = fmaf(xm, wb.x, pre[4]); pre[5] = fmaf(xm, wb.y, pre[5]);
        pre[6] = fmaf(xm, wb.z, pre[6]); pre[7] = fmaf(xm, wb.w, pre[7]);
    }
    float4 ba = *(const float4*)(b1 + d0);
    float4 bb = *(const float4*)(b1 + d0 + 4);
    float vv[8];
    vv[0] = elu1(pre[0] * inv + ba.x);
    vv[1] = elu1(pre[1] * inv + ba.y);
    vv[2] = elu1(pre[2] * inv + ba.z);
    vv[3] = elu1(pre[3] * inv + ba.w);
    vv[4] = elu1(pre[4] * inv + bb.x);
    vv[5] = elu1(pre[5] * inv + bb.y);
    vv[6] = elu1(pre[6] * inv + bb.z);
    vv[7] = elu1(pre[7] * inv + bb.w);

    // ---- fused dense-2 (round-3 proven): h2[n][j] = sum_d hL1[d]*W2[d][j] ----
    float4 av4 = *(const float4*)(as2w + j0);
    float4 dv4 = *(const float4*)(ad2w + j0);
    float p0 = 0.f, p1 = 0.f, p2 = 0.f, p3 = 0.f;
    #pragma unroll
    for (int k = 0; k < 8; k++){
        float4 wf = *(const float4*)(W2s + swz(d0 * F2 + k * F2 + j0));
        float vk = vv[k];
        p0 = fmaf(vk, wf.x, p0);
        p1 = fmaf(vk, wf.y, p1);
        p2 = fmaf(vk, wf.z, p2);
        p3 = fmaf(vk, wf.w, p3);
    }
    #pragma unroll
    for (int m = 1; m < 16; m <<= 1){
        p0 += __shfl_xor(p0, m);
        p1 += __shfl_xor(p1, m);
        p2 += __shfl_xor(p2, m);
        p3 += __shfl_xor(p3, m);
    }
    // every lane now has h2[n][j0..j0+3]
    float ps = p0 * av4.x + p1 * av4.y + p2 * av4.z + p3 * av4.w;
    float pd = p0 * dv4.x + p1 * dv4.y + p2 * dv4.z + p3 * dv4.w;
    ps += __shfl_xor(ps, 16); ps += __shfl_xor(ps, 32);
    pd += __shfl_xor(pd, 16); pd += __shfl_xor(pd, 32);
    if (lane == 0){ a_s2[n] = ps; a_d2[n] = pd; }
    if (l == 0){
        __half2 q[2];
        q[0] = __floats2half2_rn(p0, p1);
        q[1] = __floats2half2_rn(p2, p3);
        *(uint2*)(h2h + (size_t)n * F2 + j0) = *(uint2*)q;
    }
}

// ---------------- Layer 2 aggregate + classifier: 8 edge-groups x 8 lanes x 2 dims, unroll 4 ----------------
__global__ __launch_bounds__(256) void k_agg2(
    const __half* __restrict__ h2h, const float* __restrict__ a_s2, const float* __restrict__ a_d2,
    const int* __restrict__ row_ptr, const int* __restrict__ esrc,
    const float* __restrict__ b2, const float* __restrict__ Wc1, const float* __restrict__ bc1,
    const float* __restrict__ Wc2, const float* __restrict__ bc2, float* __restrict__ out){
    int t = threadIdx.x;
    int wv = t >> 6, lane = t & 63;
    int n = blockIdx.x * 4 + wv;       // N divisible by 4
    int g = lane >> 3;                 // edge subgroup (0..7)
    int l = lane & 7;                  // owns dims 2l, 2l+1
    float adn = a_d2[n];
    const __half* hb2 = h2h + 2 * l;

    float den = 0.f, acc0 = 0.f, acc1 = 0.f;
    if (g == 0){
        float w = __expf(leaky(a_s2[n] + adn));
        den = w;
        float2 f = __half22float2(*(const __half2*)(hb2 + ((unsigned)n << 4)));
        acc0 = w * f.x; acc1 = w * f.y;
    }
    int start = row_ptr[n], end = row_ptr[n + 1];
    int len = end - start;
    int chunk = (len + 7) >> 3;
    int i = start + g * chunk;
    int e = i + chunk; if (e > end) e = end;
    for (; i + 3 < e; i += 4){
        int s0 = esrc[i], s1 = esrc[i + 1], s2 = esrc[i + 2], s3 = esrc[i + 3];
        float a0 = a_s2[s0], a1 = a_s2[s1], a2 = a_s2[s2], a3 = a_s2[s3];
        __half2 p0 = *(const __half2*)(hb2 + ((unsigned)s0 << 4));
        __half2 p1 = *(const __half2*)(hb2 + ((unsigned)s1 << 4));
        __half2 p2 = *(const __half2*)(hb2 + ((unsigned)s2 << 4));
        __half2 p3 = *(const __half2*)(hb2 + ((unsigned)s3 << 4));
        float w0 = __expf(leaky(a0 + adn));
        float w1 = __expf(leaky(a1 + adn));
        float w2 = __expf(leaky(a2 + adn));
        float w3 = __expf(leaky(a3 + adn));
        den += (w0 + w1) + (w2 + w3);
        float2 f0 = __half22float2(p0), f1 = __half22float2(p1);
        float2 f2 = __half22float2(p2), f3 = __half22float2(p3);
        acc0 += w0 * f0.x + w1 * f1.x + w2 * f2.x + w3 * f3.x;
        acc1 += w0 * f0.y + w1 * f1.y + w2 * f2.y + w3 * f3.y;
    }
    for (; i < e; i++){
        int s0 = esrc[i];
        float w0 = __expf(leaky(a_s2[s0] + adn));
        float2 f0 = __half22float2(*(const __half2*)(hb2 + ((unsigned)s0 << 4)));
        den += w0;
        acc0 += w0 * f0.x; acc1 += w0 * f0.y;
    }
    #pragma unroll
    for (int off = 8; off <= 32; off <<= 1){
        den  += __shfl_xor(den, off);
        acc0 += __shfl_xor(acc0, off);
        acc1 += __shfl_xor(acc1, off);
    }
    float inv = 1.f / (den + 1e-16f);
    float e0v = elu1(acc0 * inv + b2[2 * l]);
    float e1v = elu1(acc1 * inv + b2[2 * l + 1]);
    if (g == 0){
        float2 ov; ov.x = e0v; ov.y = e1v;
        *(float2*)(out + (size_t)n * 16 + 2 * l) = ov;
    }
    // classifier: each 8-lane cluster computes the full hidden layer redundantly
    float hid = bc1[l];
    #pragma unroll
    for (int j = 0; j < 8; j++){
        float a = __shfl(e0v, j, 8);
        float b = __shfl(e1v, j, 8);
        hid += a * Wc1[(2 * j) * 8 + l] + b * Wc1[(2 * j + 1) * 8 + l];
    }
    float contrib = fmaxf(hid, 0.f) * Wc2[l];
    contrib += __shfl_xor(contrib, 1);
    contrib += __shfl_xor(contrib, 2);
    contrib += __shfl_xor(contrib, 4);
    if (lane == 0) out[(size_t)N_NODES * 16 + n] = 1.f / (1.f + __expf(-(contrib + bc2[0])));
}

extern "C" void kernel_launch(void* const* d_in, const int* in_sizes, int n_in,
                              void* d_out, int out_size, void* d_ws, size_t ws_size,
                              hipStream_t stream){
    const float* x    = (const float*)d_in[0];
    const int*   ei   = (const int*)d_in[1];
    const float* W1   = (const float*)d_in[2];
    const float* as1w = (const float*)d_in[3];
    const float* ad1w = (const float*)d_in[4];
    const float* b1   = (const float*)d_in[5];
    const float* W2   = (const float*)d_in[6];
    const float* as2w = (const float*)d_in[7];
    const float* ad2w = (const float*)d_in[8];
    const float* b2   = (const float*)d_in[9];
    const float* Wc1  = (const float*)d_in[10];
    const float* bc1  = (const float*)d_in[11];
    const float* Wc2  = (const float*)d_in[12];
    const float* bc2  = (const float*)d_in[13];
    float* out = (float*)d_out;
    const int* src = ei;
    const int* dst = ei + N_EDGES;

    float* ws   = (float*)d_ws;
    float* a_s1 = ws;                                   // N*4
    float* a_d1 = a_s1 + (size_t)N_NODES * 4;           // N*4
    float* a_s2 = a_d1 + (size_t)N_NODES * 4;           // N
    float* a_d2 = a_s2 + N_NODES;                       // N
    __half* h2h  = (__half*)(a_d2 + N_NODES);           // N*16 f16
    int* bucketCnt = (int*)(h2h + (size_t)N_NODES * 16);// NB
    int* row_ptr  = bucketCnt + NB;                     // N+1
    int* esrc     = row_ptr + N_NODES + 1;              // E
    unsigned int* ebuf = (unsigned int*)(esrc + N_EDGES); // NB*BCAP

    hipMemsetAsync(bucketCnt, 0, NB * sizeof(int), stream);
    k_bin_attn<<<NBLK_BIN + NBLK_A, 256, 0, stream>>>(
        src, dst, bucketCnt, ebuf, x, W1, as1w, ad1w, a_s1, a_d1);
    k_local_csr<<<NB, 256, 0, stream>>>(bucketCnt, ebuf, row_ptr, esrc);
    k_agg1<<<N_NODES / 4, 256, 0, stream>>>(
        x, a_s1, a_d1, row_ptr, esrc, b1, W1, W2, as2w, ad2w, h2h, a_s2, a_d2);
    k_agg2<<<N_NODES / 4, 256, 0, stream>>>(h2h, a_s2, a_d2, row_ptr, esrc, b2, Wc1, bc1, Wc2, bc2, out);
}

// Round 6
// 257.078 us; speedup vs baseline: 1.0653x; 1.0653x over previous
//
#include <hip/hip_runtime.h>
#include <hip/hip_fp16.h>
#include <math.h>

#define N_NODES 100000
#define N_EDGES 1600000
#define F_IN 8
#define HID 32
#define HEADS 4
#define F1 128    // HEADS*HID
#define F2 16     // OUT
#define NB 391          // buckets of 256 nodes
#define NBLK_BIN 391    // edge-binning blocks of 4096 edges
#define NBLK_A 391      // xa blocks of 256 nodes
#define BCAP 4864       // per-bucket capacity (mean 4092, sd ~64 -> 12 sigma)

__device__ __forceinline__ float leaky(float x){ return x > 0.f ? x : 0.2f * x; }
__device__ __forceinline__ float elu1(float x){ return x > 0.f ? x : __expf(x) - 1.f; }

// XOR swizzle for W1s (dword addr): element a stored at a ^ (bit5(a)<<2).
// Read pattern (round-5 proven): base = swz1(row + 8q) holds elems [8q..8q+3]
// in order; the OTHER float4 of the fragment is at base ^ 4 (involution, NOT +4).
__device__ __forceinline__ int swz1(int a){ return a ^ (((a >> 5) & 1) << 2); }

// ---------------- Fused: edge binning (blocks 0..390) + xa build (rest) ----------------
// xa[n][16] = { x[n][0:8], a_s1[n][0:4], a_d1[n][0:4] } -- one 64 B row holding
// everything the aggregation loop needs per gather (one cache line per edge).
// a_s1[n,h] = x[n,:]·c_s[h,:] with c_s[h] = W1_h @ att_s[h] (h1 never materialized).
__global__ __launch_bounds__(256) void k_bin_attn(
    const int* __restrict__ src, const int* __restrict__ dst,
    int* __restrict__ bucketCnt, unsigned int* __restrict__ ebuf,
    const float* __restrict__ x, const float* __restrict__ W1,
    const float* __restrict__ as1w, const float* __restrict__ ad1w,
    float* __restrict__ xa){
    __shared__ float smem[1344];
    int t = threadIdx.x;
    if (blockIdx.x < NBLK_BIN){
        // ---- edge binning: 4096 edges -> 391 coarse buckets, line-local writes ----
        int* hist    = (int*)smem;
        int* basePos = hist + NB;
        int* cur     = basePos + NB;
        for (int j = t; j < NB; j += 256) hist[j] = 0;
        __syncthreads();
        int base = blockIdx.x * 4096;
        int dv[16];                        // register-cache dst (skip re-read in scatter pass)
        #pragma unroll
        for (int j = 0; j < 16; j++){
            int e = base + j * 256 + t;
            dv[j] = (e < N_EDGES) ? dst[e] : -1;
            if (dv[j] >= 0) atomicAdd(&hist[dv[j] >> 8], 1);
        }
        __syncthreads();
        for (int j = t; j < NB; j += 256){
            int h = hist[j];
            if (h) basePos[j] = atomicAdd(&bucketCnt[j], h);
            cur[j] = 0;
        }
        __syncthreads();
        #pragma unroll
        for (int j = 0; j < 16; j++){
            if (dv[j] >= 0){
                int e = base + j * 256 + t;
                int d = dv[j];
                int b = d >> 8;
                int off = atomicAdd(&cur[b], 1);
                ebuf[b * BCAP + basePos[b] + off] = ((unsigned)(d & 255) << 17) | (unsigned)src[e];
            }
        }
    } else {
        // ---- attention dots: c = W1·att (tiny), then xa row per node ----
        float* W1s  = smem;          // 1024
        float* atts = smem + 1024;   // 128
        float* attd = smem + 1152;   // 128
        float* cs   = smem + 1280;   // 32  (cs[h*8+m])
        float* cd   = smem + 1312;   // 32
        ((float4*)W1s)[t] = ((const float4*)W1)[t];
        if (t < 128){ atts[t] = as1w[t]; attd[t] = ad1w[t]; }
        __syncthreads();
        if (t < 64){
            int m = t & 7, h = (t >> 3) & 3;
            bool sel = t >= 32;
            const float* wrow = W1s + m * F1 + h * 32;
            const float* av   = (sel ? attd : atts) + h * 32;
            float s = 0.f;
            #pragma unroll
            for (int d = 0; d < 32; d++) s += wrow[d] * av[d];
            (sel ? cd : cs)[h * 8 + m] = s;
        }
        __syncthreads();
        int n = (blockIdx.x - NBLK_BIN) * 256 + t;
        if (n < N_NODES){
            float4 x0 = ((const float4*)x)[n * 2];
            float4 x1 = ((const float4*)x)[n * 2 + 1];
            float4 osv, odv;
            float* po = (float*)&osv;
            float* pd = (float*)&odv;
            #pragma unroll
            for (int h = 0; h < 4; h++){
                const float* c0 = cs + h * 8;
                const float* c1 = cd + h * 8;
                po[h] = x0.x*c0[0] + x0.y*c0[1] + x0.z*c0[2] + x0.w*c0[3]
                      + x1.x*c0[4] + x1.y*c0[5] + x1.z*c0[6] + x1.w*c0[7];
                pd[h] = x0.x*c1[0] + x0.y*c1[1] + x0.z*c1[2] + x0.w*c1[3]
                      + x1.x*c1[4] + x1.y*c1[5] + x1.z*c1[6] + x1.w*c1[7];
            }
            float* px = xa + (size_t)n * 16;
            *(float4*)(px)      = x0;
            *(float4*)(px + 4)  = x1;
            *(float4*)(px + 8)  = osv;
            *(float4*)(px + 12) = odv;
        }
    }
}

// ---------------- CSR pass 2: one 256-thread block per bucket ----------------
__global__ __launch_bounds__(256) void k_local_csr(
    const int* __restrict__ bucketCnt, const unsigned int* __restrict__ ebuf,
    int* __restrict__ row_ptr, int* __restrict__ esrc){
    __shared__ int deg[256];
    __shared__ int scn[256];
    __shared__ int cntAll[NB];
    __shared__ unsigned int segs[BCAP];   // LDS cache of this bucket's edges (19.5 KB)
    int b = blockIdx.x, t = threadIdx.x;
    deg[t] = 0;
    for (int j = t; j < NB; j += 256) cntAll[j] = bucketCnt[j];
    __syncthreads();
    // parallel bucket-prefix: sum cntAll[0..b) across all 256 threads
    int partial = 0;
    for (int j = t; j < b; j += 256) partial += cntAll[j];
    scn[t] = partial;
    __syncthreads();
    for (int off = 128; off > 0; off >>= 1){
        if (t < off) scn[t] += scn[t + off];
        __syncthreads();
    }
    int sbase = scn[0];
    int cnt = cntAll[b];
    __syncthreads();
    const unsigned int* seg = ebuf + b * BCAP;
    for (int i = t; i < cnt; i += 256){
        unsigned int e = seg[i];
        segs[i] = e;                      // cache for scatter pass (kills 2nd global read)
        atomicAdd(&deg[e >> 17], 1);
    }
    __syncthreads();
    int v = deg[t];
    scn[t] = v;
    __syncthreads();
    for (int off = 1; off < 256; off <<= 1){
        int xx = (t >= off) ? scn[t - off] : 0;
        __syncthreads();
        scn[t] += xx;
        __syncthreads();
    }
    int excl = scn[t] - v;
    int start = sbase + excl;
    int n = b * 256 + t;
    if (n < N_NODES) row_ptr[n] = start;
    if (b == NB - 1 && t == 0) row_ptr[N_NODES] = sbase + cnt;
    deg[t] = start;            // reuse as global cursor
    __syncthreads();
    for (int i = t; i < cnt; i += 256){
        unsigned int e = segs[i];
        int pos = atomicAdd(&deg[e >> 17], 1);
        esrc[pos] = (int)(e & 0x1FFFFu);
    }
}

// ---------------- Layer 1 aggregate (x-space), slim: loop + reduce + write ----------------
// 4 edge-groups (g) x 16 lanes (l); lane owns head hd=l>>2, x-dim pair 2c,2c+1.
// Per edge: ONE dword gather (lane l reads xa[s*16+l]; 16 lanes = one 64 B line)
// + 3 width-16 shfls to redistribute a_s1[hd] / x[2c] / x[2c+1]. No LDS at all.
// Heavy dense epilogue moved to k_epi (round-5 lesson: epilogue dominated VALU).
__global__ __launch_bounds__(256) void k_agg1(
    const float* __restrict__ xa, const int* __restrict__ row_ptr, const int* __restrict__ esrc,
    float* __restrict__ xagg, float* __restrict__ dden){
    int t = threadIdx.x;
    int wv = t >> 6, lane = t & 63;
    int n = blockIdx.x * 4 + wv;               // N divisible by 4
    int g = lane >> 4;                          // edge subgroup (0..3)
    int l = lane & 15;
    int hd = l >> 2;                            // head
    int c2 = (l & 3) * 2;                       // x-dim pair: c2, c2+1

    // node's own xa row: element l per lane; adh broadcast from lane 12+hd
    float vn = xa[(size_t)n * 16 + l];
    float adh = __shfl(vn, 12 + hd, 16);

    float den = 0.f, ac0 = 0.f, ac1 = 0.f;
    if (g == 0){
        // self-loop (softmax shift m=0; logits O(1), fp32 acc)
        float w = __expf(leaky(__shfl(vn, 8 + hd, 16) + adh));
        den = w;
        ac0 = w * __shfl(vn, c2, 16);
        ac1 = w * __shfl(vn, c2 + 1, 16);
    }
    int start = row_ptr[n], end = row_ptr[n + 1];
    int len = end - start;
    int chunk = (len + 3) >> 2;
    int i = start + g * chunk;
    int e = i + chunk; if (e > end) e = end;
    for (; i + 3 < e; i += 4){
        int s0 = esrc[i], s1 = esrc[i + 1], s2 = esrc[i + 2], s3 = esrc[i + 3];
        float v0 = xa[(size_t)s0 * 16 + l];
        float v1 = xa[(size_t)s1 * 16 + l];
        float v2 = xa[(size_t)s2 * 16 + l];
        float v3 = xa[(size_t)s3 * 16 + l];
        float w0 = __expf(leaky(__shfl(v0, 8 + hd, 16) + adh));
        float w1 = __expf(leaky(__shfl(v1, 8 + hd, 16) + adh));
        float w2 = __expf(leaky(__shfl(v2, 8 + hd, 16) + adh));
        float w3 = __expf(leaky(__shfl(v3, 8 + hd, 16) + adh));
        den += (w0 + w1) + (w2 + w3);
        ac0 = fmaf(w0, __shfl(v0, c2, 16), ac0); ac1 = fmaf(w0, __shfl(v0, c2 + 1, 16), ac1);
        ac0 = fmaf(w1, __shfl(v1, c2, 16), ac0); ac1 = fmaf(w1, __shfl(v1, c2 + 1, 16), ac1);
        ac0 = fmaf(w2, __shfl(v2, c2, 16), ac0); ac1 = fmaf(w2, __shfl(v2, c2 + 1, 16), ac1);
        ac0 = fmaf(w3, __shfl(v3, c2, 16), ac0); ac1 = fmaf(w3, __shfl(v3, c2 + 1, 16), ac1);
    }
    for (; i < e; i++){
        int s0 = esrc[i];
        float v0 = xa[(size_t)s0 * 16 + l];
        float w0 = __expf(leaky(__shfl(v0, 8 + hd, 16) + adh));
        den += w0;
        ac0 = fmaf(w0, __shfl(v0, c2, 16), ac0); ac1 = fmaf(w0, __shfl(v0, c2 + 1, 16), ac1);
    }
    // combine the four edge-groups (lanes xor16/xor32 share l)
    den += __shfl_xor(den, 16); den += __shfl_xor(den, 32);
    ac0 += __shfl_xor(ac0, 16); ac0 += __shfl_xor(ac0, 32);
    ac1 += __shfl_xor(ac1, 16); ac1 += __shfl_xor(ac1, 32);

    if (lane < 16){
        // xagg[n][hd*8 + c2 .. +1] == xagg[n][2l .. 2l+1]: 16 lanes -> 128 B coalesced
        float2 o; o.x = ac0; o.y = ac1;
        *(float2*)(xagg + (size_t)n * 32 + 2 * l) = o;
        if ((l & 3) == 0) dden[(size_t)n * 4 + hd] = den;
    }
}

// ---------------- Dense epilogue: hL1 = elu(xagg@W1/den + b1); h2 = hL1@W2 ----------------
// 16 nodes x 16 threads per block. Phase 1: thread (nn,q) computes hL1 dims
// 8q..8q+7 (no redundancy) -> LDS hls (stride 132 to spread banks). Phase 2
// (round-0 k_dense2 pattern, proven): thread (nn,dim) dots hls row with W2
// column (W2s reads are 16-bank broadcast-clean), then a_s2/a_d2 + h2h (fp16).
__global__ __launch_bounds__(256) void k_epi(
    const float* __restrict__ xagg, const float* __restrict__ dden,
    const float* __restrict__ W1, const float* __restrict__ W2,
    const float* __restrict__ b1, const float* __restrict__ as2w, const float* __restrict__ ad2w,
    __half* __restrict__ h2h, float* __restrict__ a_s2, float* __restrict__ a_d2){
    __shared__ float W1s[F_IN * F1];   // 4 KB, swz1-swizzled
    __shared__ float W2s[F1 * F2];     // 8 KB, linear [128][16]
    __shared__ float hls[16 * 132];    // 8.25 KB, padded stride
    int t = threadIdx.x;
    *(float4*)(W1s + swz1(4 * t)) = ((const float4*)W1)[t];
    ((float4*)W2s)[t]       = ((const float4*)W2)[t];
    ((float4*)W2s)[t + 256] = ((const float4*)W2)[t + 256];
    __syncthreads();

    int nn = t >> 4, q = t & 15;
    int n = blockIdx.x * 16 + nn;              // N divisible by 16
    int hd = q >> 2;

    // ---- phase 1: hL1 dims 8q..8q+7 ----
    const float* xg = xagg + (size_t)n * 32 + hd * 8;
    float4 xga = *(const float4*)(xg);
    float4 xgb = *(const float4*)(xg + 4);
    float invd = 1.f / dden[(size_t)n * 4 + hd];
    float xv[8] = {xga.x, xga.y, xga.z, xga.w, xgb.x, xgb.y, xgb.z, xgb.w};
    float pre[8] = {0,0,0,0,0,0,0,0};
    #pragma unroll
    for (int m = 0; m < 8; m++){
        int base = swz1(m * F1 + 8 * q);
        float4 wa = *(const float4*)(W1s + base);        // dims 8q..8q+3 (in order)
        float4 wb = *(const float4*)(W1s + (base ^ 4));  // dims 8q+4..8q+7
        float xm = xv[m];
        pre[0] = fmaf(xm, wa.x, pre[0]); pre[1] = fmaf(xm, wa.y, pre[1]);
        pre[2] = fmaf(xm, wa.z, pre[2]); pre[3] = fmaf(xm, wa.w, pre[3]);
        pre[4] = fmaf(xm, wb.x, pre[4]); pre[5] = fmaf(xm, wb.y, pre[5]);
        pre[6] = fmaf(xm, wb.z, pre[6]); pre[7] = fmaf(xm, wb.w, pre[7]);
    }
    float4 ba = *(const float4*)(b1 + 8 * q);
    float4 bb = *(const float4*)(b1 + 8 * q + 4);
    float4 o0, o1;
    o0.x = elu1(pre[0] * invd + ba.x); o0.y = elu1(pre[1] * invd + ba.y);
    o0.z = elu1(pre[2] * invd + ba.z); o0.w = elu1(pre[3] * invd + ba.w);
    o1.x = elu1(pre[4] * invd + bb.x); o1.y = elu1(pre[5] * invd + bb.y);
    o1.z = elu1(pre[6] * invd + bb.z); o1.w = elu1(pre[7] * invd + bb.w);
    *(float4*)(hls + nn * 132 + 8 * q)     = o0;
    *(float4*)(hls + nn * 132 + 8 * q + 4) = o1;
    __syncthreads();

    // ---- phase 2: h2[n][dim] = hls[nn][:] . W2[:][dim] ----
    int dim = q;
    const float* hrow = hls + nn * 132;
    float dot = 0.f;
    #pragma unroll 8
    for (int k2 = 0; k2 < 64; k2++){
        float2 f = *(const float2*)(hrow + 2 * k2);
        dot += f.x * W2s[(2 * k2) * F2 + dim] + f.y * W2s[(2 * k2 + 1) * F2 + dim];
    }
    float ps = dot * as2w[dim];
    float pd = dot * ad2w[dim];
    #pragma unroll
    for (int off = 8; off >= 1; off >>= 1){
        ps += __shfl_down(ps, off, 16);
        pd += __shfl_down(pd, off, 16);
    }
    if (dim == 0){ a_s2[n] = ps; a_d2[n] = pd; }
    h2h[(size_t)n * F2 + dim] = __float2half(dot);
}

// ---------------- Layer 2 aggregate + classifier: 8 edge-groups x 8 lanes x 2 dims, unroll 4 ----------------
__global__ __launch_bounds__(256) void k_agg2(
    const __half* __restrict__ h2h, const float* __restrict__ a_s2, const float* __restrict__ a_d2,
    const int* __restrict__ row_ptr, const int* __restrict__ esrc,
    const float* __restrict__ b2, const float* __restrict__ Wc1, const float* __restrict__ bc1,
    const float* __restrict__ Wc2, const float* __restrict__ bc2, float* __restrict__ out){
    int t = threadIdx.x;
    int wv = t >> 6, lane = t & 63;
    int n = blockIdx.x * 4 + wv;       // N divisible by 4
    int g = lane >> 3;                 // edge subgroup (0..7)
    int l = lane & 7;                  // owns dims 2l, 2l+1
    float adn = a_d2[n];
    const __half* hb2 = h2h + 2 * l;

    float den = 0.f, acc0 = 0.f, acc1 = 0.f;
    if (g == 0){
        float w = __expf(leaky(a_s2[n] + adn));
        den = w;
        float2 f = __half22float2(*(const __half2*)(hb2 + ((unsigned)n << 4)));
        acc0 = w * f.x; acc1 = w * f.y;
    }
    int start = row_ptr[n], end = row_ptr[n + 1];
    int len = end - start;
    int chunk = (len + 7) >> 3;
    int i = start + g * chunk;
    int e = i + chunk; if (e > end) e = end;
    for (; i + 3 < e; i += 4){
        int s0 = esrc[i], s1 = esrc[i + 1], s2 = esrc[i + 2], s3 = esrc[i + 3];
        float a0 = a_s2[s0], a1 = a_s2[s1], a2 = a_s2[s2], a3 = a_s2[s3];
        __half2 p0 = *(const __half2*)(hb2 + ((unsigned)s0 << 4));
        __half2 p1 = *(const __half2*)(hb2 + ((unsigned)s1 << 4));
        __half2 p2 = *(const __half2*)(hb2 + ((unsigned)s2 << 4));
        __half2 p3 = *(const __half2*)(hb2 + ((unsigned)s3 << 4));
        float w0 = __expf(leaky(a0 + adn));
        float w1 = __expf(leaky(a1 + adn));
        float w2 = __expf(leaky(a2 + adn));
        float w3 = __expf(leaky(a3 + adn));
        den += (w0 + w1) + (w2 + w3);
        float2 f0 = __half22float2(p0), f1 = __half22float2(p1);
        float2 f2 = __half22float2(p2), f3 = __half22float2(p3);
        acc0 += w0 * f0.x + w1 * f1.x + w2 * f2.x + w3 * f3.x;
        acc1 += w0 * f0.y + w1 * f1.y + w2 * f2.y + w3 * f3.y;
    }
    for (; i < e; i++){
        int s0 = esrc[i];
        float w0 = __expf(leaky(a_s2[s0] + adn));
        float2 f0 = __half22float2(*(const __half2*)(hb2 + ((unsigned)s0 << 4)));
        den += w0;
        acc0 += w0 * f0.x; acc1 += w0 * f0.y;
    }
    #pragma unroll
    for (int off = 8; off <= 32; off <<= 1){
        den  += __shfl_xor(den, off);
        acc0 += __shfl_xor(acc0, off);
        acc1 += __shfl_xor(acc1, off);
    }
    float inv = 1.f / (den + 1e-16f);
    float e0v = elu1(acc0 * inv + b2[2 * l]);
    float e1v = elu1(acc1 * inv + b2[2 * l + 1]);
    if (g == 0){
        float2 ov; ov.x = e0v; ov.y = e1v;
        *(float2*)(out + (size_t)n * 16 + 2 * l) = ov;
    }
    // classifier: each 8-lane cluster computes the full hidden layer redundantly
    float hid = bc1[l];
    #pragma unroll
    for (int j = 0; j < 8; j++){
        float a = __shfl(e0v, j, 8);
        float b = __shfl(e1v, j, 8);
        hid += a * Wc1[(2 * j) * 8 + l] + b * Wc1[(2 * j + 1) * 8 + l];
    }
    float contrib = fmaxf(hid, 0.f) * Wc2[l];
    contrib += __shfl_xor(contrib, 1);
    contrib += __shfl_xor(contrib, 2);
    contrib += __shfl_xor(contrib, 4);
    if (lane == 0) out[(size_t)N_NODES * 16 + n] = 1.f / (1.f + __expf(-(contrib + bc2[0])));
}

extern "C" void kernel_launch(void* const* d_in, const int* in_sizes, int n_in,
                              void* d_out, int out_size, void* d_ws, size_t ws_size,
                              hipStream_t stream){
    const float* x    = (const float*)d_in[0];
    const int*   ei   = (const int*)d_in[1];
    const float* W1   = (const float*)d_in[2];
    const float* as1w = (const float*)d_in[3];
    const float* ad1w = (const float*)d_in[4];
    const float* b1   = (const float*)d_in[5];
    const float* W2   = (const float*)d_in[6];
    const float* as2w = (const float*)d_in[7];
    const float* ad2w = (const float*)d_in[8];
    const float* b2   = (const float*)d_in[9];
    const float* Wc1  = (const float*)d_in[10];
    const float* bc1  = (const float*)d_in[11];
    const float* Wc2  = (const float*)d_in[12];
    const float* bc2  = (const float*)d_in[13];
    float* out = (float*)d_out;
    const int* src = ei;
    const int* dst = ei + N_EDGES;

    float* ws   = (float*)d_ws;
    float* a_s2 = ws;                                   // N
    float* a_d2 = a_s2 + N_NODES;                       // N
    float* xa   = a_d2 + N_NODES;                       // N*16
    float* xagg = xa + (size_t)N_NODES * 16;            // N*32
    float* dden = xagg + (size_t)N_NODES * 32;          // N*4
    __half* h2h = (__half*)(dden + (size_t)N_NODES * 4);// N*16 f16
    int* bucketCnt = (int*)(h2h + (size_t)N_NODES * 16);// NB
    int* row_ptr  = bucketCnt + NB;                     // N+1
    int* esrc     = row_ptr + N_NODES + 1;              // E
    unsigned int* ebuf = (unsigned int*)(esrc + N_EDGES); // NB*BCAP

    hipMemsetAsync(bucketCnt, 0, NB * sizeof(int), stream);
    k_bin_attn<<<NBLK_BIN + NBLK_A, 256, 0, stream>>>(
        src, dst, bucketCnt, ebuf, x, W1, as1w, ad1w, xa);
    k_local_csr<<<NB, 256, 0, stream>>>(bucketCnt, ebuf, row_ptr, esrc);
    k_agg1<<<N_NODES / 4, 256, 0, stream>>>(xa, row_ptr, esrc, xagg, dden);
    k_epi<<<N_NODES / 16, 256, 0, stream>>>(
        xagg, dden, W1, W2, b1, as2w, ad2w, h2h, a_s2, a_d2);
    k_agg2<<<N_NODES / 4, 256, 0, stream>>>(h2h, a_s2, a_d2, row_ptr, esrc, b2, Wc1, bc1, Wc2, bc2, out);
}

// Round 7
// 253.876 us; speedup vs baseline: 1.0788x; 1.0126x over previous
//
#include <hip/hip_runtime.h>
#include <hip/hip_fp16.h>
#include <math.h>

#define N_NODES 100000
#define N_EDGES 1600000
#define F_IN 8
#define HID 32
#define HEADS 4
#define F1 128    // HEADS*HID
#define F2 16     // OUT
#define NB 391          // buckets of 256 nodes
#define NBLK_BIN 391    // edge-binning blocks of 4096 edges
#define NBLK_A 391      // xa blocks of 256 nodes
#define BCAP 4864       // per-bucket capacity (mean 4092, sd ~64 -> 12 sigma)

__device__ __forceinline__ float leaky(float x){ return x > 0.f ? x : 0.2f * x; }
__device__ __forceinline__ float elu1(float x){ return x > 0.f ? x : __expf(x) - 1.f; }

// XOR swizzle for W1s (dword addr): element a stored at a ^ (bit5(a)<<2).
// Read pattern (round-5 proven): base = swz1(row + 8q) holds elems [8q..8q+3]
// in order; the OTHER float4 of the fragment is at base ^ 4 (involution, NOT +4).
__device__ __forceinline__ int swz1(int a){ return a ^ (((a >> 5) & 1) << 2); }

// ---------------- Fused: edge binning (blocks 0..390) + xa build (rest) ----------------
// xa[n][16] = { x[n][0:8], a_s1[n][0:4], a_d1[n][0:4] } -- one 64 B row holding
// everything the aggregation loop needs per gather (one cache line per edge).
// a_s1[n,h] = x[n,:]·c_s[h,:] with c_s[h] = W1_h @ att_s[h] (h1 never materialized).
__global__ __launch_bounds__(256) void k_bin_attn(
    const int* __restrict__ src, const int* __restrict__ dst,
    int* __restrict__ bucketCnt, unsigned int* __restrict__ ebuf,
    const float* __restrict__ x, const float* __restrict__ W1,
    const float* __restrict__ as1w, const float* __restrict__ ad1w,
    float* __restrict__ xa){
    __shared__ float smem[1344];
    int t = threadIdx.x;
    if (blockIdx.x < NBLK_BIN){
        // ---- edge binning: 4096 edges -> 391 coarse buckets, line-local writes ----
        int* hist    = (int*)smem;
        int* basePos = hist + NB;
        int* cur     = basePos + NB;
        for (int j = t; j < NB; j += 256) hist[j] = 0;
        __syncthreads();
        int base = blockIdx.x * 4096;
        int dv[16];                        // register-cache dst (skip re-read in scatter pass)
        #pragma unroll
        for (int j = 0; j < 16; j++){
            int e = base + j * 256 + t;
            dv[j] = (e < N_EDGES) ? dst[e] : -1;
            if (dv[j] >= 0) atomicAdd(&hist[dv[j] >> 8], 1);
        }
        __syncthreads();
        for (int j = t; j < NB; j += 256){
            int h = hist[j];
            if (h) basePos[j] = atomicAdd(&bucketCnt[j], h);
            cur[j] = 0;
        }
        __syncthreads();
        #pragma unroll
        for (int j = 0; j < 16; j++){
            if (dv[j] >= 0){
                int e = base + j * 256 + t;
                int d = dv[j];
                int b = d >> 8;
                int off = atomicAdd(&cur[b], 1);
                ebuf[b * BCAP + basePos[b] + off] = ((unsigned)(d & 255) << 17) | (unsigned)src[e];
            }
        }
    } else {
        // ---- attention dots: c = W1·att (tiny), then xa row per node ----
        float* W1s  = smem;          // 1024
        float* atts = smem + 1024;   // 128
        float* attd = smem + 1152;   // 128
        float* cs   = smem + 1280;   // 32  (cs[h*8+m])
        float* cd   = smem + 1312;   // 32
        ((float4*)W1s)[t] = ((const float4*)W1)[t];
        if (t < 128){ atts[t] = as1w[t]; attd[t] = ad1w[t]; }
        __syncthreads();
        if (t < 64){
            int m = t & 7, h = (t >> 3) & 3;
            bool sel = t >= 32;
            const float* wrow = W1s + m * F1 + h * 32;
            const float* av   = (sel ? attd : atts) + h * 32;
            float s = 0.f;
            #pragma unroll
            for (int d = 0; d < 32; d++) s += wrow[d] * av[d];
            (sel ? cd : cs)[h * 8 + m] = s;
        }
        __syncthreads();
        int n = (blockIdx.x - NBLK_BIN) * 256 + t;
        if (n < N_NODES){
            float4 x0 = ((const float4*)x)[n * 2];
            float4 x1 = ((const float4*)x)[n * 2 + 1];
            float4 osv, odv;
            float* po = (float*)&osv;
            float* pd = (float*)&odv;
            #pragma unroll
            for (int h = 0; h < 4; h++){
                const float* c0 = cs + h * 8;
                const float* c1 = cd + h * 8;
                po[h] = x0.x*c0[0] + x0.y*c0[1] + x0.z*c0[2] + x0.w*c0[3]
                      + x1.x*c0[4] + x1.y*c0[5] + x1.z*c0[6] + x1.w*c0[7];
                pd[h] = x0.x*c1[0] + x0.y*c1[1] + x0.z*c1[2] + x0.w*c1[3]
                      + x1.x*c1[4] + x1.y*c1[5] + x1.z*c1[6] + x1.w*c1[7];
            }
            float* px = xa + (size_t)n * 16;
            *(float4*)(px)      = x0;
            *(float4*)(px + 4)  = x1;
            *(float4*)(px + 8)  = osv;
            *(float4*)(px + 12) = odv;
        }
    }
}

// ---------------- CSR pass 2: one 256-thread block per bucket ----------------
__global__ __launch_bounds__(256) void k_local_csr(
    const int* __restrict__ bucketCnt, const unsigned int* __restrict__ ebuf,
    int* __restrict__ row_ptr, int* __restrict__ esrc){
    __shared__ int deg[256];
    __shared__ int scn[256];
    __shared__ int cntAll[NB];
    __shared__ unsigned int segs[BCAP];   // LDS cache of this bucket's edges (19.5 KB)
    int b = blockIdx.x, t = threadIdx.x;
    deg[t] = 0;
    for (int j = t; j < NB; j += 256) cntAll[j] = bucketCnt[j];
    __syncthreads();
    // parallel bucket-prefix: sum cntAll[0..b) across all 256 threads
    int partial = 0;
    for (int j = t; j < b; j += 256) partial += cntAll[j];
    scn[t] = partial;
    __syncthreads();
    for (int off = 128; off > 0; off >>= 1){
        if (t < off) scn[t] += scn[t + off];
        __syncthreads();
    }
    int sbase = scn[0];
    int cnt = cntAll[b];
    __syncthreads();
    const unsigned int* seg = ebuf + b * BCAP;
    for (int i = t; i < cnt; i += 256){
        unsigned int e = seg[i];
        segs[i] = e;                      // cache for scatter pass (kills 2nd global read)
        atomicAdd(&deg[e >> 17], 1);
    }
    __syncthreads();
    int v = deg[t];
    scn[t] = v;
    __syncthreads();
    for (int off = 1; off < 256; off <<= 1){
        int xx = (t >= off) ? scn[t - off] : 0;
        __syncthreads();
        scn[t] += xx;
        __syncthreads();
    }
    int excl = scn[t] - v;
    int start = sbase + excl;
    int n = b * 256 + t;
    if (n < N_NODES) row_ptr[n] = start;
    if (b == NB - 1 && t == 0) row_ptr[N_NODES] = sbase + cnt;
    deg[t] = start;            // reuse as global cursor
    __syncthreads();
    for (int i = t; i < cnt; i += 256){
        unsigned int e = segs[i];
        int pos = atomicAdd(&deg[e >> 17], 1);
        esrc[pos] = (int)(e & 0x1FFFFu);
    }
}

// ---------------- Layer 1 aggregate (x-space), slim: loop + reduce + write ----------------
// 4 edge-groups (g) x 16 lanes (l); lane owns head hd=l>>2, x-dim pair 2c,2c+1.
// Per edge: ONE dword gather (lane l reads xa[s*16+l]; 16 lanes = one 64 B line)
// + 3 width-16 shfls to redistribute a_s1[hd] / x[2c] / x[2c+1]. No LDS at all.
// Heavy dense epilogue moved to k_epi (round-5 lesson: epilogue dominated VALU).
__global__ __launch_bounds__(256) void k_agg1(
    const float* __restrict__ xa, const int* __restrict__ row_ptr, const int* __restrict__ esrc,
    float* __restrict__ xagg, float* __restrict__ dden){
    int t = threadIdx.x;
    int wv = t >> 6, lane = t & 63;
    int n = blockIdx.x * 4 + wv;               // N divisible by 4
    int g = lane >> 4;                          // edge subgroup (0..3)
    int l = lane & 15;
    int hd = l >> 2;                            // head
    int c2 = (l & 3) * 2;                       // x-dim pair: c2, c2+1

    // node's own xa row: element l per lane; adh broadcast from lane 12+hd
    float vn = xa[(size_t)n * 16 + l];
    float adh = __shfl(vn, 12 + hd, 16);

    float den = 0.f, ac0 = 0.f, ac1 = 0.f;
    if (g == 0){
        // self-loop (softmax shift m=0; logits O(1), fp32 acc)
        float w = __expf(leaky(__shfl(vn, 8 + hd, 16) + adh));
        den = w;
        ac0 = w * __shfl(vn, c2, 16);
        ac1 = w * __shfl(vn, c2 + 1, 16);
    }
    int start = row_ptr[n], end = row_ptr[n + 1];
    int len = end - start;
    int chunk = (len + 3) >> 2;
    int i = start + g * chunk;
    int e = i + chunk; if (e > end) e = end;
    for (; i + 3 < e; i += 4){
        int s0 = esrc[i], s1 = esrc[i + 1], s2 = esrc[i + 2], s3 = esrc[i + 3];
        float v0 = xa[(size_t)s0 * 16 + l];
        float v1 = xa[(size_t)s1 * 16 + l];
        float v2 = xa[(size_t)s2 * 16 + l];
        float v3 = xa[(size_t)s3 * 16 + l];
        float w0 = __expf(leaky(__shfl(v0, 8 + hd, 16) + adh));
        float w1 = __expf(leaky(__shfl(v1, 8 + hd, 16) + adh));
        float w2 = __expf(leaky(__shfl(v2, 8 + hd, 16) + adh));
        float w3 = __expf(leaky(__shfl(v3, 8 + hd, 16) + adh));
        den += (w0 + w1) + (w2 + w3);
        ac0 = fmaf(w0, __shfl(v0, c2, 16), ac0); ac1 = fmaf(w0, __shfl(v0, c2 + 1, 16), ac1);
        ac0 = fmaf(w1, __shfl(v1, c2, 16), ac0); ac1 = fmaf(w1, __shfl(v1, c2 + 1, 16), ac1);
        ac0 = fmaf(w2, __shfl(v2, c2, 16), ac0); ac1 = fmaf(w2, __shfl(v2, c2 + 1, 16), ac1);
        ac0 = fmaf(w3, __shfl(v3, c2, 16), ac0); ac1 = fmaf(w3, __shfl(v3, c2 + 1, 16), ac1);
    }
    for (; i < e; i++){
        int s0 = esrc[i];
        float v0 = xa[(size_t)s0 * 16 + l];
        float w0 = __expf(leaky(__shfl(v0, 8 + hd, 16) + adh));
        den += w0;
        ac0 = fmaf(w0, __shfl(v0, c2, 16), ac0); ac1 = fmaf(w0, __shfl(v0, c2 + 1, 16), ac1);
    }
    // combine the four edge-groups (lanes xor16/xor32 share l)
    den += __shfl_xor(den, 16); den += __shfl_xor(den, 32);
    ac0 += __shfl_xor(ac0, 16); ac0 += __shfl_xor(ac0, 32);
    ac1 += __shfl_xor(ac1, 16); ac1 += __shfl_xor(ac1, 32);

    if (lane < 16){
        // xagg[n][hd*8 + c2 .. +1] == xagg[n][2l .. 2l+1]: 16 lanes -> 128 B coalesced
        float2 o; o.x = ac0; o.y = ac1;
        *(float2*)(xagg + (size_t)n * 32 + 2 * l) = o;
        if ((l & 3) == 0) dden[(size_t)n * 4 + hd] = den;
    }
}

// ---------------- Dense epilogue: hL1 = elu(xagg@W1/den + b1); h2 = hL1@W2 ----------------
// 16 nodes x 16 threads per block. Phase 1: thread (nn,q) computes hL1 dims
// 8q..8q+7 (no redundancy) -> LDS hls (stride 132 to spread banks). Phase 2
// (round-0 k_dense2 pattern, proven): thread (nn,dim) dots hls row with W2
// column (W2s reads are 16-bank broadcast-clean), then a_s2/a_d2 + h2h (fp16).
__global__ __launch_bounds__(256) void k_epi(
    const float* __restrict__ xagg, const float* __restrict__ dden,
    const float* __restrict__ W1, const float* __restrict__ W2,
    const float* __restrict__ b1, const float* __restrict__ as2w, const float* __restrict__ ad2w,
    __half* __restrict__ h2h, float* __restrict__ a_s2, float* __restrict__ a_d2){
    __shared__ float W1s[F_IN * F1];   // 4 KB, swz1-swizzled
    __shared__ float W2s[F1 * F2];     // 8 KB, linear [128][16]
    __shared__ float hls[16 * 132];    // 8.25 KB, padded stride
    int t = threadIdx.x;
    *(float4*)(W1s + swz1(4 * t)) = ((const float4*)W1)[t];
    ((float4*)W2s)[t]       = ((const float4*)W2)[t];
    ((float4*)W2s)[t + 256] = ((const float4*)W2)[t + 256];
    __syncthreads();

    int nn = t >> 4, q = t & 15;
    int n = blockIdx.x * 16 + nn;              // N divisible by 16
    int hd = q >> 2;

    // ---- phase 1: hL1 dims 8q..8q+7 ----
    const float* xg = xagg + (size_t)n * 32 + hd * 8;
    float4 xga = *(const float4*)(xg);
    float4 xgb = *(const float4*)(xg + 4);
    float invd = 1.f / dden[(size_t)n * 4 + hd];
    float xv[8] = {xga.x, xga.y, xga.z, xga.w, xgb.x, xgb.y, xgb.z, xgb.w};
    float pre[8] = {0,0,0,0,0,0,0,0};
    #pragma unroll
    for (int m = 0; m < 8; m++){
        int base = swz1(m * F1 + 8 * q);
        float4 wa = *(const float4*)(W1s + base);        // dims 8q..8q+3 (in order)
        float4 wb = *(const float4*)(W1s + (base ^ 4));  // dims 8q+4..8q+7
        float xm = xv[m];
        pre[0] = fmaf(xm, wa.x, pre[0]); pre[1] = fmaf(xm, wa.y, pre[1]);
        pre[2] = fmaf(xm, wa.z, pre[2]); pre[3] = fmaf(xm, wa.w, pre[3]);
        pre[4] = fmaf(xm, wb.x, pre[4]); pre[5] = fmaf(xm, wb.y, pre[5]);
        pre[6] = fmaf(xm, wb.z, pre[6]); pre[7] = fmaf(xm, wb.w, pre[7]);
    }
    float4 ba = *(const float4*)(b1 + 8 * q);
    float4 bb = *(const float4*)(b1 + 8 * q + 4);
    float4 o0, o1;
    o0.x = elu1(pre[0] * invd + ba.x); o0.y = elu1(pre[1] * invd + ba.y);
    o0.z = elu1(pre[2] * invd + ba.z); o0.w = elu1(pre[3] * invd + ba.w);
    o1.x = elu1(pre[4] * invd + bb.x); o1.y = elu1(pre[5] * invd + bb.y);
    o1.z = elu1(pre[6] * invd + bb.z); o1.w = elu1(pre[7] * invd + bb.w);
    *(float4*)(hls + nn * 132 + 8 * q)     = o0;
    *(float4*)(hls + nn * 132 + 8 * q + 4) = o1;
    __syncthreads();

    // ---- phase 2: h2[n][dim] = hls[nn][:] . W2[:][dim] ----
    int dim = q;
    const float* hrow = hls + nn * 132;
    float dot = 0.f;
    #pragma unroll 8
    for (int k2 = 0; k2 < 64; k2++){
        float2 f = *(const float2*)(hrow + 2 * k2);
        dot += f.x * W2s[(2 * k2) * F2 + dim] + f.y * W2s[(2 * k2 + 1) * F2 + dim];
    }
    float ps = dot * as2w[dim];
    float pd = dot * ad2w[dim];
    #pragma unroll
    for (int off = 8; off >= 1; off >>= 1){
        ps += __shfl_down(ps, off, 16);
        pd += __shfl_down(pd, off, 16);
    }
    if (dim == 0){ a_s2[n] = ps; a_d2[n] = pd; }
    h2h[(size_t)n * F2 + dim] = __float2half(dot);
}

// ---------------- Layer 2 aggregate + classifier ----------------
// 8 edge-groups x 8 lanes x 2 dims. Round-6 lesson: with mean degree ~17,
// chunk = ceil(deg/8) ~ 2-3, so an unroll-4 + scalar-remainder structure puts
// ALL edges on the scalar path: 2-3 SERIAL dependent gather chains per wave
// (~1100 exposed cycles, VALUBusy 57%). Fix: predicated 4-wide batches --
// always issue 4 index loads (invalid slots clamped to s0) and all 8 gathers
// concurrently; zero invalid weights. Every chunk = 1 (rarely 2) load chains.
__global__ __launch_bounds__(256) void k_agg2(
    const __half* __restrict__ h2h, const float* __restrict__ a_s2, const float* __restrict__ a_d2,
    const int* __restrict__ row_ptr, const int* __restrict__ esrc,
    const float* __restrict__ b2, const float* __restrict__ Wc1, const float* __restrict__ bc1,
    const float* __restrict__ Wc2, const float* __restrict__ bc2, float* __restrict__ out){
    int t = threadIdx.x;
    int wv = t >> 6, lane = t & 63;
    int n = blockIdx.x * 4 + wv;       // N divisible by 4
    int g = lane >> 3;                 // edge subgroup (0..7)
    int l = lane & 7;                  // owns dims 2l, 2l+1
    float adn = a_d2[n];
    const __half* hb2 = h2h + 2 * l;

    float den = 0.f, acc0 = 0.f, acc1 = 0.f;
    if (g == 0){
        float w = __expf(leaky(a_s2[n] + adn));
        den = w;
        float2 f = __half22float2(*(const __half2*)(hb2 + ((unsigned)n << 4)));
        acc0 = w * f.x; acc1 = w * f.y;
    }
    int start = row_ptr[n], end = row_ptr[n + 1];
    int len = end - start;
    int chunk = (len + 7) >> 3;
    int i = start + g * chunk;
    int e = i + chunk; if (e > end) e = end;
    for (int base = i; base < e; base += 4){
        bool v1 = base + 1 < e, v2 = base + 2 < e, v3 = base + 3 < e;
        int s0 = esrc[base];
        int s1 = v1 ? esrc[base + 1] : s0;
        int s2 = v2 ? esrc[base + 2] : s0;
        int s3 = v3 ? esrc[base + 3] : s0;
        float a0 = a_s2[s0], a1 = a_s2[s1], a2 = a_s2[s2], a3 = a_s2[s3];
        __half2 p0 = *(const __half2*)(hb2 + ((unsigned)s0 << 4));
        __half2 p1 = *(const __half2*)(hb2 + ((unsigned)s1 << 4));
        __half2 p2 = *(const __half2*)(hb2 + ((unsigned)s2 << 4));
        __half2 p3 = *(const __half2*)(hb2 + ((unsigned)s3 << 4));
        float w0 = __expf(leaky(a0 + adn));
        float w1 = v1 ? __expf(leaky(a1 + adn)) : 0.f;
        float w2 = v2 ? __expf(leaky(a2 + adn)) : 0.f;
        float w3 = v3 ? __expf(leaky(a3 + adn)) : 0.f;
        den += (w0 + w1) + (w2 + w3);
        float2 f0 = __half22float2(p0), f1 = __half22float2(p1);
        float2 f2 = __half22float2(p2), f3 = __half22float2(p3);
        acc0 += w0 * f0.x + w1 * f1.x + w2 * f2.x + w3 * f3.x;
        acc1 += w0 * f0.y + w1 * f1.y + w2 * f2.y + w3 * f3.y;
    }
    #pragma unroll
    for (int off = 8; off <= 32; off <<= 1){
        den  += __shfl_xor(den, off);
        acc0 += __shfl_xor(acc0, off);
        acc1 += __shfl_xor(acc1, off);
    }
    float inv = 1.f / (den + 1e-16f);
    float e0v = elu1(acc0 * inv + b2[2 * l]);
    float e1v = elu1(acc1 * inv + b2[2 * l + 1]);
    if (g == 0){
        float2 ov; ov.x = e0v; ov.y = e1v;
        *(float2*)(out + (size_t)n * 16 + 2 * l) = ov;
    }
    // classifier: each 8-lane cluster computes the full hidden layer redundantly
    float hid = bc1[l];
    #pragma unroll
    for (int j = 0; j < 8; j++){
        float a = __shfl(e0v, j, 8);
        float b = __shfl(e1v, j, 8);
        hid += a * Wc1[(2 * j) * 8 + l] + b * Wc1[(2 * j + 1) * 8 + l];
    }
    float contrib = fmaxf(hid, 0.f) * Wc2[l];
    contrib += __shfl_xor(contrib, 1);
    contrib += __shfl_xor(contrib, 2);
    contrib += __shfl_xor(contrib, 4);
    if (lane == 0) out[(size_t)N_NODES * 16 + n] = 1.f / (1.f + __expf(-(contrib + bc2[0])));
}

extern "C" void kernel_launch(void* const* d_in, const int* in_sizes, int n_in,
                              void* d_out, int out_size, void* d_ws, size_t ws_size,
                              hipStream_t stream){
    const float* x    = (const float*)d_in[0];
    const int*   ei   = (const int*)d_in[1];
    const float* W1   = (const float*)d_in[2];
    const float* as1w = (const float*)d_in[3];
    const float* ad1w = (const float*)d_in[4];
    const float* b1   = (const float*)d_in[5];
    const float* W2   = (const float*)d_in[6];
    const float* as2w = (const float*)d_in[7];
    const float* ad2w = (const float*)d_in[8];
    const float* b2   = (const float*)d_in[9];
    const float* Wc1  = (const float*)d_in[10];
    const float* bc1  = (const float*)d_in[11];
    const float* Wc2  = (const float*)d_in[12];
    const float* bc2  = (const float*)d_in[13];
    float* out = (float*)d_out;
    const int* src = ei;
    const int* dst = ei + N_EDGES;

    float* ws   = (float*)d_ws;
    float* a_s2 = ws;                                   // N
    float* a_d2 = a_s2 + N_NODES;                       // N
    float* xa   = a_d2 + N_NODES;                       // N*16
    float* xagg = xa + (size_t)N_NODES * 16;            // N*32
    float* dden = xagg + (size_t)N_NODES * 32;          // N*4
    __half* h2h = (__half*)(dden + (size_t)N_NODES * 4);// N*16 f16
    int* bucketCnt = (int*)(h2h + (size_t)N_NODES * 16);// NB
    int* row_ptr  = bucketCnt + NB;                     // N+1
    int* esrc     = row_ptr + N_NODES + 1;              // E
    unsigned int* ebuf = (unsigned int*)(esrc + N_EDGES); // NB*BCAP

    hipMemsetAsync(bucketCnt, 0, NB * sizeof(int), stream);
    k_bin_attn<<<NBLK_BIN + NBLK_A, 256, 0, stream>>>(
        src, dst, bucketCnt, ebuf, x, W1, as1w, ad1w, xa);
    k_local_csr<<<NB, 256, 0, stream>>>(bucketCnt, ebuf, row_ptr, esrc);
    k_agg1<<<N_NODES / 4, 256, 0, stream>>>(xa, row_ptr, esrc, xagg, dden);
    k_epi<<<N_NODES / 16, 256, 0, stream>>>(
        xagg, dden, W1, W2, b1, as2w, ad2w, h2h, a_s2, a_d2);
    k_agg2<<<N_NODES / 4, 256, 0, stream>>>(h2h, a_s2, a_d2, row_ptr, esrc, b2, Wc1, bc1, Wc2, bc2, out);
}

// Round 8
// 242.104 us; speedup vs baseline: 1.1312x; 1.0486x over previous
//
#include <hip/hip_runtime.h>
#include <hip/hip_fp16.h>
#include <math.h>

#define N_NODES 100000
#define N_EDGES 1600000
#define F_IN 8
#define HID 32
#define HEADS 4
#define F1 128    // HEADS*HID
#define F2 16     // OUT
#define NB 391          // buckets of 256 nodes
#define NBLK_BIN 391    // edge-binning blocks of 4096 edges
#define NBLK_A 391      // xa blocks of 256 nodes
#define BCAP 4864       // per-bucket capacity (mean 4092, sd ~64 -> 12 sigma)

__device__ __forceinline__ float leaky(float x){ return x > 0.f ? x : 0.2f * x; }
__device__ __forceinline__ float elu1(float x){ return x > 0.f ? x : __expf(x) - 1.f; }

// ---------------- Fused: edge binning (blocks 0..390) + xa build (rest) ----------------
// xa[n][16] = { x[n][0:8], a_s1[n][0:4], a_d1[n][0:4] } -- one 64 B row holding
// everything the aggregation loop needs per gather (one cache line per edge).
// a_s1[n,h] = x[n,:]·c_s[h,:] with c_s[h] = W1_h @ att_s[h] (h1 never materialized).
__global__ __launch_bounds__(256) void k_bin_attn(
    const int* __restrict__ src, const int* __restrict__ dst,
    int* __restrict__ bucketCnt, unsigned int* __restrict__ ebuf,
    const float* __restrict__ x, const float* __restrict__ W1,
    const float* __restrict__ as1w, const float* __restrict__ ad1w,
    float* __restrict__ xa){
    __shared__ float smem[1344];
    int t = threadIdx.x;
    if (blockIdx.x < NBLK_BIN){
        // ---- edge binning: 4096 edges -> 391 coarse buckets, line-local writes ----
        int* hist    = (int*)smem;
        int* basePos = hist + NB;
        int* cur     = basePos + NB;
        for (int j = t; j < NB; j += 256) hist[j] = 0;
        __syncthreads();
        int base = blockIdx.x * 4096;
        int dv[16];                        // register-cache dst (skip re-read in scatter pass)
        #pragma unroll
        for (int j = 0; j < 16; j++){
            int e = base + j * 256 + t;
            dv[j] = (e < N_EDGES) ? dst[e] : -1;
            if (dv[j] >= 0) atomicAdd(&hist[dv[j] >> 8], 1);
        }
        __syncthreads();
        for (int j = t; j < NB; j += 256){
            int h = hist[j];
            if (h) basePos[j] = atomicAdd(&bucketCnt[j], h);
            cur[j] = 0;
        }
        __syncthreads();
        #pragma unroll
        for (int j = 0; j < 16; j++){
            if (dv[j] >= 0){
                int e = base + j * 256 + t;
                int d = dv[j];
                int b = d >> 8;
                int off = atomicAdd(&cur[b], 1);
                ebuf[b * BCAP + basePos[b] + off] = ((unsigned)(d & 255) << 17) | (unsigned)src[e];
            }
        }
    } else {
        // ---- attention dots: c = W1·att (tiny), then xa row per node ----
        float* W1s  = smem;          // 1024
        float* atts = smem + 1024;   // 128
        float* attd = smem + 1152;   // 128
        float* cs   = smem + 1280;   // 32  (cs[h*8+m])
        float* cd   = smem + 1312;   // 32
        ((float4*)W1s)[t] = ((const float4*)W1)[t];
        if (t < 128){ atts[t] = as1w[t]; attd[t] = ad1w[t]; }
        __syncthreads();
        if (t < 64){
            int m = t & 7, h = (t >> 3) & 3;
            bool sel = t >= 32;
            const float* wrow = W1s + m * F1 + h * 32;
            const float* av   = (sel ? attd : atts) + h * 32;
            float s = 0.f;
            #pragma unroll
            for (int d = 0; d < 32; d++) s += wrow[d] * av[d];
            (sel ? cd : cs)[h * 8 + m] = s;
        }
        __syncthreads();
        int n = (blockIdx.x - NBLK_BIN) * 256 + t;
        if (n < N_NODES){
            float4 x0 = ((const float4*)x)[n * 2];
            float4 x1 = ((const float4*)x)[n * 2 + 1];
            float4 osv, odv;
            float* po = (float*)&osv;
            float* pd = (float*)&odv;
            #pragma unroll
            for (int h = 0; h < 4; h++){
                const float* c0 = cs + h * 8;
                const float* c1 = cd + h * 8;
                po[h] = x0.x*c0[0] + x0.y*c0[1] + x0.z*c0[2] + x0.w*c0[3]
                      + x1.x*c0[4] + x1.y*c0[5] + x1.z*c0[6] + x1.w*c0[7];
                pd[h] = x0.x*c1[0] + x0.y*c1[1] + x0.z*c1[2] + x0.w*c1[3]
                      + x1.x*c1[4] + x1.y*c1[5] + x1.z*c1[6] + x1.w*c1[7];
            }
            float* px = xa + (size_t)n * 16;
            *(float4*)(px)      = x0;
            *(float4*)(px + 4)  = x1;
            *(float4*)(px + 8)  = osv;
            *(float4*)(px + 12) = odv;
        }
    }
}

// ---------------- CSR pass 2: one 256-thread block per bucket ----------------
__global__ __launch_bounds__(256) void k_local_csr(
    const int* __restrict__ bucketCnt, const unsigned int* __restrict__ ebuf,
    int* __restrict__ row_ptr, int* __restrict__ esrc){
    __shared__ int deg[256];
    __shared__ int scn[256];
    __shared__ int cntAll[NB];
    __shared__ unsigned int segs[BCAP];   // LDS cache of this bucket's edges (19.5 KB)
    int b = blockIdx.x, t = threadIdx.x;
    deg[t] = 0;
    for (int j = t; j < NB; j += 256) cntAll[j] = bucketCnt[j];
    __syncthreads();
    // parallel bucket-prefix: sum cntAll[0..b) across all 256 threads
    int partial = 0;
    for (int j = t; j < b; j += 256) partial += cntAll[j];
    scn[t] = partial;
    __syncthreads();
    for (int off = 128; off > 0; off >>= 1){
        if (t < off) scn[t] += scn[t + off];
        __syncthreads();
    }
    int sbase = scn[0];
    int cnt = cntAll[b];
    __syncthreads();
    const unsigned int* seg = ebuf + b * BCAP;
    for (int i = t; i < cnt; i += 256){
        unsigned int e = seg[i];
        segs[i] = e;                      // cache for scatter pass (kills 2nd global read)
        atomicAdd(&deg[e >> 17], 1);
    }
    __syncthreads();
    int v = deg[t];
    scn[t] = v;
    __syncthreads();
    for (int off = 1; off < 256; off <<= 1){
        int xx = (t >= off) ? scn[t - off] : 0;
        __syncthreads();
        scn[t] += xx;
        __syncthreads();
    }
    int excl = scn[t] - v;
    int start = sbase + excl;
    int n = b * 256 + t;
    if (n < N_NODES) row_ptr[n] = start;
    if (b == NB - 1 && t == 0) row_ptr[N_NODES] = sbase + cnt;
    deg[t] = start;            // reuse as global cursor
    __syncthreads();
    for (int i = t; i < cnt; i += 256){
        unsigned int e = segs[i];
        int pos = atomicAdd(&deg[e >> 17], 1);
        esrc[pos] = (int)(e & 0x1FFFFu);
    }
}

// ---------------- Layer 1 aggregate (x-space), slim: loop + reduce + write ----------------
// 4 edge-groups (g) x 16 lanes (l); lane owns head hd=l>>2, x-dim pair 2c,2c+1.
// Per edge: ONE dword gather (lane l reads xa[s*16+l]; 16 lanes = one 64 B line)
// + 3 width-16 shfls to redistribute a_s1[hd] / x[2c] / x[2c+1]. No LDS at all.
__global__ __launch_bounds__(256) void k_agg1(
    const float* __restrict__ xa, const int* __restrict__ row_ptr, const int* __restrict__ esrc,
    float* __restrict__ xagg, float* __restrict__ dden){
    int t = threadIdx.x;
    int wv = t >> 6, lane = t & 63;
    int n = blockIdx.x * 4 + wv;               // N divisible by 4
    int g = lane >> 4;                          // edge subgroup (0..3)
    int l = lane & 15;
    int hd = l >> 2;                            // head
    int c2 = (l & 3) * 2;                       // x-dim pair: c2, c2+1

    // node's own xa row: element l per lane; adh broadcast from lane 12+hd
    float vn = xa[(size_t)n * 16 + l];
    float adh = __shfl(vn, 12 + hd, 16);

    float den = 0.f, ac0 = 0.f, ac1 = 0.f;
    if (g == 0){
        // self-loop (softmax shift m=0; logits O(1), fp32 acc)
        float w = __expf(leaky(__shfl(vn, 8 + hd, 16) + adh));
        den = w;
        ac0 = w * __shfl(vn, c2, 16);
        ac1 = w * __shfl(vn, c2 + 1, 16);
    }
    int start = row_ptr[n], end = row_ptr[n + 1];
    int len = end - start;
    int chunk = (len + 3) >> 2;
    int i = start + g * chunk;
    int e = i + chunk; if (e > end) e = end;
    for (; i + 3 < e; i += 4){
        int s0 = esrc[i], s1 = esrc[i + 1], s2 = esrc[i + 2], s3 = esrc[i + 3];
        float v0 = xa[(size_t)s0 * 16 + l];
        float v1 = xa[(size_t)s1 * 16 + l];
        float v2 = xa[(size_t)s2 * 16 + l];
        float v3 = xa[(size_t)s3 * 16 + l];
        float w0 = __expf(leaky(__shfl(v0, 8 + hd, 16) + adh));
        float w1 = __expf(leaky(__shfl(v1, 8 + hd, 16) + adh));
        float w2 = __expf(leaky(__shfl(v2, 8 + hd, 16) + adh));
        float w3 = __expf(leaky(__shfl(v3, 8 + hd, 16) + adh));
        den += (w0 + w1) + (w2 + w3);
        ac0 = fmaf(w0, __shfl(v0, c2, 16), ac0); ac1 = fmaf(w0, __shfl(v0, c2 + 1, 16), ac1);
        ac0 = fmaf(w1, __shfl(v1, c2, 16), ac0); ac1 = fmaf(w1, __shfl(v1, c2 + 1, 16), ac1);
        ac0 = fmaf(w2, __shfl(v2, c2, 16), ac0); ac1 = fmaf(w2, __shfl(v2, c2 + 1, 16), ac1);
        ac0 = fmaf(w3, __shfl(v3, c2, 16), ac0); ac1 = fmaf(w3, __shfl(v3, c2 + 1, 16), ac1);
    }
    for (; i < e; i++){
        int s0 = esrc[i];
        float v0 = xa[(size_t)s0 * 16 + l];
        float w0 = __expf(leaky(__shfl(v0, 8 + hd, 16) + adh));
        den += w0;
        ac0 = fmaf(w0, __shfl(v0, c2, 16), ac0); ac1 = fmaf(w0, __shfl(v0, c2 + 1, 16), ac1);
    }
    // combine the four edge-groups (lanes xor16/xor32 share l)
    den += __shfl_xor(den, 16); den += __shfl_xor(den, 32);
    ac0 += __shfl_xor(ac0, 16); ac0 += __shfl_xor(ac0, 32);
    ac1 += __shfl_xor(ac1, 16); ac1 += __shfl_xor(ac1, 32);

    if (lane < 16){
        // xagg[n][hd*8 + c2 .. +1] == xagg[n][2l .. 2l+1]: 16 lanes -> 128 B coalesced
        float2 o; o.x = ac0; o.y = ac1;
        *(float2*)(xagg + (size_t)n * 32 + 2 * l) = o;
        if ((l & 3) == 0) dden[(size_t)n * 4 + hd] = den;
    }
}

// ---------------- Dense epilogue (round-7 lesson: was LDS-instr-throughput-bound) ----------------
// hL1 = elu(xagg@W1/den + b1); h2 = hL1@W2. 16 nodes x 16 threads per block.
// fp16-packed LDS with b128 reads only: 48 LDS wave-instrs/node -> ~10.
//  W1h[m][dim-pair]   : phase-1 row fragment = 1 b128 per m (8 dims).
//  W2t[dim][k-pair]   : TRANSPOSED so a thread's W2 column is contiguous ->
//                       16 b128; dim-stride 64 dwords == 0 mod 32 banks, so
//                       XOR bits[8:6] into [4:2] (8 spans x 2-way = free).
//  hlsh[nn][k-pair]   : row stride 68; phase-2 hrow = 16 b128 (broadcast over q).
// Inner product in __hfma2, flushed to f32 every 8 terms (bounded fp16 chains).
__global__ __launch_bounds__(256) void k_epi(
    const float* __restrict__ xagg, const float* __restrict__ dden,
    const float* __restrict__ W1, const float* __restrict__ W2,
    const float* __restrict__ b1, const float* __restrict__ as2w, const float* __restrict__ ad2w,
    __half* __restrict__ h2h, float* __restrict__ a_s2, float* __restrict__ a_d2){
    __shared__ __half2 W1h[F_IN * 64];   // 2 KB
    __shared__ __half2 W2t[F2 * 64];     // 4 KB, swizzled
    __shared__ __half2 hlsh[16 * 68];    // 4.25 KB
    int t = threadIdx.x;
    {
        // W1h: thread t covers W1 elems 4t..4t+3 -> m = t>>5, dim-pairs (2t)&63, +1
        float4 w1v = ((const float4*)W1)[t];
        int m = t >> 5, j = (2 * t) & 63;
        W1h[m * 64 + j]     = __floats2half2_rn(w1v.x, w1v.y);
        W1h[m * 64 + j + 1] = __floats2half2_rn(w1v.z, w1v.w);
        // W2t: transpose-scatter two float4s (one-time half-granular writes)
        #pragma unroll
        for (int hf = 0; hf < 2; hf++){
            int p = t + hf * 256;
            float4 wv = ((const float4*)W2)[p];
            int k = p >> 2, dbase = (p & 3) * 4;
            float vals[4] = {wv.x, wv.y, wv.z, wv.w};
            #pragma unroll
            for (int c = 0; c < 4; c++){
                int dw = (dbase + c) * 64 + (k >> 1);
                int sdw = dw ^ (((dw >> 6) & 7) << 2);
                ((__half*)W2t)[2 * sdw + (k & 1)] = __float2half(vals[c]);
            }
        }
    }
    __syncthreads();

    int nn = t >> 4, q = t & 15;
    int n = blockIdx.x * 16 + nn;              // N divisible by 16
    int hd = q >> 2;

    // ---- phase 1: hL1 dims 8q..8q+7 ----
    const float* xg = xagg + (size_t)n * 32 + hd * 8;
    float4 xga = *(const float4*)(xg);
    float4 xgb = *(const float4*)(xg + 4);
    float invd = 1.f / dden[(size_t)n * 4 + hd];
    float xv[8] = {xga.x, xga.y, xga.z, xga.w, xgb.x, xgb.y, xgb.z, xgb.w};
    float pre[8] = {0,0,0,0,0,0,0,0};
    #pragma unroll
    for (int m = 0; m < 8; m++){
        float4 raw = *(const float4*)(W1h + m * 64 + 4 * q);   // conflict-free: q-consecutive
        const __half2* wp = (const __half2*)&raw;
        float xm = xv[m];
        float2 f0 = __half22float2(wp[0]);
        float2 f1 = __half22float2(wp[1]);
        float2 f2 = __half22float2(wp[2]);
        float2 f3 = __half22float2(wp[3]);
        pre[0] = fmaf(xm, f0.x, pre[0]); pre[1] = fmaf(xm, f0.y, pre[1]);
        pre[2] = fmaf(xm, f1.x, pre[2]); pre[3] = fmaf(xm, f1.y, pre[3]);
        pre[4] = fmaf(xm, f2.x, pre[4]); pre[5] = fmaf(xm, f2.y, pre[5]);
        pre[6] = fmaf(xm, f3.x, pre[6]); pre[7] = fmaf(xm, f3.y, pre[7]);
    }
    float4 ba = *(const float4*)(b1 + 8 * q);
    float4 bb = *(const float4*)(b1 + 8 * q + 4);
    __half2 hout[4];
    hout[0] = __floats2half2_rn(elu1(pre[0] * invd + ba.x), elu1(pre[1] * invd + ba.y));
    hout[1] = __floats2half2_rn(elu1(pre[2] * invd + ba.z), elu1(pre[3] * invd + ba.w));
    hout[2] = __floats2half2_rn(elu1(pre[4] * invd + bb.x), elu1(pre[5] * invd + bb.y));
    hout[3] = __floats2half2_rn(elu1(pre[6] * invd + bb.z), elu1(pre[7] * invd + bb.w));
    *(float4*)(hlsh + nn * 68 + 4 * q) = *(float4*)hout;
    __syncthreads();

    // ---- phase 2: h2[n][q] = hL1 . W2col(q), fp16 packed, f32 flush every 8 terms ----
    float dot = 0.f;
    #pragma unroll
    for (int ob = 0; ob < 8; ob++){
        __half2 acc2 = __float2half2_rn(0.f);
        #pragma unroll
        for (int kb = ob * 2; kb < ob * 2 + 2; kb++){
            float4 hr = *(const float4*)(hlsh + nn * 68 + 4 * kb);
            int dwb = 64 * q + 4 * kb;
            float4 wr = *(const float4*)(W2t + (dwb ^ (((dwb >> 6) & 7) << 2)));
            const __half2* hp  = (const __half2*)&hr;
            const __half2* wp2 = (const __half2*)&wr;
            acc2 = __hfma2(hp[0], wp2[0], acc2);
            acc2 = __hfma2(hp[1], wp2[1], acc2);
            acc2 = __hfma2(hp[2], wp2[2], acc2);
            acc2 = __hfma2(hp[3], wp2[3], acc2);
        }
        float2 fa = __half22float2(acc2);
        dot += fa.x + fa.y;
    }
    float ps = dot * as2w[q];
    float pd = dot * ad2w[q];
    #pragma unroll
    for (int off = 8; off >= 1; off >>= 1){
        ps += __shfl_down(ps, off, 16);
        pd += __shfl_down(pd, off, 16);
    }
    if (q == 0){ a_s2[n] = ps; a_d2[n] = pd; }
    h2h[(size_t)n * F2 + q] = __float2half(dot);
}

// ---------------- Layer 2 aggregate + classifier (round-7 predicated batching) ----------------
__global__ __launch_bounds__(256) void k_agg2(
    const __half* __restrict__ h2h, const float* __restrict__ a_s2, const float* __restrict__ a_d2,
    const int* __restrict__ row_ptr, const int* __restrict__ esrc,
    const float* __restrict__ b2, const float* __restrict__ Wc1, const float* __restrict__ bc1,
    const float* __restrict__ Wc2, const float* __restrict__ bc2, float* __restrict__ out){
    int t = threadIdx.x;
    int wv = t >> 6, lane = t & 63;
    int n = blockIdx.x * 4 + wv;       // N divisible by 4
    int g = lane >> 3;                 // edge subgroup (0..7)
    int l = lane & 7;                  // owns dims 2l, 2l+1
    float adn = a_d2[n];
    const __half* hb2 = h2h + 2 * l;

    float den = 0.f, acc0 = 0.f, acc1 = 0.f;
    if (g == 0){
        float w = __expf(leaky(a_s2[n] + adn));
        den = w;
        float2 f = __half22float2(*(const __half2*)(hb2 + ((unsigned)n << 4)));
        acc0 = w * f.x; acc1 = w * f.y;
    }
    int start = row_ptr[n], end = row_ptr[n + 1];
    int len = end - start;
    int chunk = (len + 7) >> 3;
    int i = start + g * chunk;
    int e = i + chunk; if (e > end) e = end;
    for (int base = i; base < e; base += 4){
        bool v1 = base + 1 < e, v2 = base + 2 < e, v3 = base + 3 < e;
        int s0 = esrc[base];
        int s1 = v1 ? esrc[base + 1] : s0;
        int s2 = v2 ? esrc[base + 2] : s0;
        int s3 = v3 ? esrc[base + 3] : s0;
        float a0 = a_s2[s0], a1 = a_s2[s1], a2 = a_s2[s2], a3 = a_s2[s3];
        __half2 p0 = *(const __half2*)(hb2 + ((unsigned)s0 << 4));
        __half2 p1 = *(const __half2*)(hb2 + ((unsigned)s1 << 4));
        __half2 p2 = *(const __half2*)(hb2 + ((unsigned)s2 << 4));
        __half2 p3 = *(const __half2*)(hb2 + ((unsigned)s3 << 4));
        float w0 = __expf(leaky(a0 + adn));
        float w1 = v1 ? __expf(leaky(a1 + adn)) : 0.f;
        float w2 = v2 ? __expf(leaky(a2 + adn)) : 0.f;
        float w3 = v3 ? __expf(leaky(a3 + adn)) : 0.f;
        den += (w0 + w1) + (w2 + w3);
        float2 f0 = __half22float2(p0), f1 = __half22float2(p1);
        float2 f2 = __half22float2(p2), f3 = __half22float2(p3);
        acc0 += w0 * f0.x + w1 * f1.x + w2 * f2.x + w3 * f3.x;
        acc1 += w0 * f0.y + w1 * f1.y + w2 * f2.y + w3 * f3.y;
    }
    #pragma unroll
    for (int off = 8; off <= 32; off <<= 1){
        den  += __shfl_xor(den, off);
        acc0 += __shfl_xor(acc0, off);
        acc1 += __shfl_xor(acc1, off);
    }
    float inv = 1.f / (den + 1e-16f);
    float e0v = elu1(acc0 * inv + b2[2 * l]);
    float e1v = elu1(acc1 * inv + b2[2 * l + 1]);
    if (g == 0){
        float2 ov; ov.x = e0v; ov.y = e1v;
        *(float2*)(out + (size_t)n * 16 + 2 * l) = ov;
    }
    // classifier: each 8-lane cluster computes the full hidden layer redundantly
    float hid = bc1[l];
    #pragma unroll
    for (int j = 0; j < 8; j++){
        float a = __shfl(e0v, j, 8);
        float b = __shfl(e1v, j, 8);
        hid += a * Wc1[(2 * j) * 8 + l] + b * Wc1[(2 * j + 1) * 8 + l];
    }
    float contrib = fmaxf(hid, 0.f) * Wc2[l];
    contrib += __shfl_xor(contrib, 1);
    contrib += __shfl_xor(contrib, 2);
    contrib += __shfl_xor(contrib, 4);
    if (lane == 0) out[(size_t)N_NODES * 16 + n] = 1.f / (1.f + __expf(-(contrib + bc2[0])));
}

extern "C" void kernel_launch(void* const* d_in, const int* in_sizes, int n_in,
                              void* d_out, int out_size, void* d_ws, size_t ws_size,
                              hipStream_t stream){
    const float* x    = (const float*)d_in[0];
    const int*   ei   = (const int*)d_in[1];
    const float* W1   = (const float*)d_in[2];
    const float* as1w = (const float*)d_in[3];
    const float* ad1w = (const float*)d_in[4];
    const float* b1   = (const float*)d_in[5];
    const float* W2   = (const float*)d_in[6];
    const float* as2w = (const float*)d_in[7];
    const float* ad2w = (const float*)d_in[8];
    const float* b2   = (const float*)d_in[9];
    const float* Wc1  = (const float*)d_in[10];
    const float* bc1  = (const float*)d_in[11];
    const float* Wc2  = (const float*)d_in[12];
    const float* bc2  = (const float*)d_in[13];
    float* out = (float*)d_out;
    const int* src = ei;
    const int* dst = ei + N_EDGES;

    float* ws   = (float*)d_ws;
    float* a_s2 = ws;                                   // N
    float* a_d2 = a_s2 + N_NODES;                       // N
    float* xa   = a_d2 + N_NODES;                       // N*16
    float* xagg = xa + (size_t)N_NODES * 16;            // N*32
    float* dden = xagg + (size_t)N_NODES * 32;          // N*4
    __half* h2h = (__half*)(dden + (size_t)N_NODES * 4);// N*16 f16
    int* bucketCnt = (int*)(h2h + (size_t)N_NODES * 16);// NB
    int* row_ptr  = bucketCnt + NB;                     // N+1
    int* esrc     = row_ptr + N_NODES + 1;              // E
    unsigned int* ebuf = (unsigned int*)(esrc + N_EDGES); // NB*BCAP

    hipMemsetAsync(bucketCnt, 0, NB * sizeof(int), stream);
    k_bin_attn<<<NBLK_BIN + NBLK_A, 256, 0, stream>>>(
        src, dst, bucketCnt, ebuf, x, W1, as1w, ad1w, xa);
    k_local_csr<<<NB, 256, 0, stream>>>(bucketCnt, ebuf, row_ptr, esrc);
    k_agg1<<<N_NODES / 4, 256, 0, stream>>>(xa, row_ptr, esrc, xagg, dden);
    k_epi<<<N_NODES / 16, 256, 0, stream>>>(
        xagg, dden, W1, W2, b1, as2w, ad2w, h2h, a_s2, a_d2);
    k_agg2<<<N_NODES / 4, 256, 0, stream>>>(h2h, a_s2, a_d2, row_ptr, esrc, b2, Wc1, bc1, Wc2, bc2, out);
}